// Round 1
// baseline (460.896 us; speedup 1.0000x reference)
//
#include <hip/hip_runtime.h>
#include <math.h>

#define NB 2048
#define LL 200
#define DD 128
#define AA 64
#define LT 32
#define NEG_INF_F -4294967295.0f  // rounds to -2^32 in fp32, same as reference's -2^32+1

// One block per batch row b. 256 threads.
// Layer-1 folding: [q,k,q-k,q*k]@W1 = qW + k@Wq with per-batch Wq (128x64).
__global__ __launch_bounds__(256, 2)
void din_fused(const float* __restrict__ query,
               const float* __restrict__ keys,
               const int*   __restrict__ keys_length,
               const float* __restrict__ W1,
               const float* __restrict__ b1,
               const float* __restrict__ a1p,
               const float* __restrict__ W2,
               const float* __restrict__ b2,
               const float* __restrict__ a2p,
               const float* __restrict__ W3,
               float* __restrict__ out,
               float* __restrict__ att)
{
    __shared__ float sWq[DD * AA];   // 8192 f: folded per-batch weight [d][a]
    __shared__ float sKW[LT * 132];  // 4224 f: keys tile (padded) / W2 reuse
    __shared__ float sH[LT * 68];    // 2176 f: h1 tile (padded) / phase-3 scratch
    __shared__ float sQ[DD];
    __shared__ float sQW[AA];
    __shared__ float sS[224];        // scores, 7*32
    __shared__ float sRed[256];

    const int tid = threadIdx.x;
    const int b   = blockIdx.x;
    const int len = keys_length[b];
    const float pa1 = a1p[0];
    const float pa2 = a2p[0];

    if (tid < DD) sQ[tid] = query[(size_t)b * DD + tid];
    for (int i = tid; i < 224; i += 256) sS[i] = NEG_INF_F;
    __syncthreads();

    // Wq[d][a] = (W1b - W1c)[d][a] + q[d]*W1d[d][a]
    for (int i = tid; i < DD * AA; i += 256) {
        const int d = i >> 6, a = i & 63;
        sWq[i] = W1[(DD + d) * AA + a] - W1[(2 * DD + d) * AA + a]
               + sQ[d] * W1[(3 * DD + d) * AA + a];
    }
    // qW[a] = b1[a] + sum_d q[d]*(W1a + W1c)[d][a]   (4 partial groups of 32 d)
    {
        const int a = tid & 63, p = tid >> 6;
        float acc = 0.f;
        const int d0 = p * 32;
        for (int d = d0; d < d0 + 32; ++d)
            acc += sQ[d] * (W1[d * AA + a] + W1[(2 * DD + d) * AA + a]);
        sRed[tid] = acc;
    }
    __syncthreads();
    if (tid < AA)
        sQW[tid] = b1[tid] + sRed[tid] + sRed[64 + tid] + sRed[128 + tid] + sRed[192 + tid];

    const int tr = tid >> 4, tc = tid & 15;   // 16x16 thread grid
    const int r0 = tr * 2, c0 = tc * 4;       // micro-tile: 2 rows x 4 cols
    const float4 bb2 = *(const float4*)&b2[c0];
    const float4 w3v = *(const float4*)&W3[c0];

    const int ntiles = (len + LT - 1) / LT;   // only score l < len; rest stays NEG_INF

    for (int t = 0; t < ntiles; ++t) {
        const int l0 = t * LT;
        __syncthreads();  // sQW ready (t==0); prev-iter sKW/sH readers done
        // stage keys tile -> sKW [row][132]
        for (int i = tid; i < LT * DD / 4; i += 256) {
            const int row = i >> 5, c4 = i & 31;
            const int l = l0 + row;
            float4 v = make_float4(0.f, 0.f, 0.f, 0.f);
            if (l < LL) v = *(const float4*)(keys + ((size_t)b * LL + l) * DD + c4 * 4);
            *(float4*)&sKW[row * 132 + c4 * 4] = v;
        }
        __syncthreads();

        // ---- GEMM1: (32 x 64) = keysTile(32x128) @ Wq(128x64), init qW ----
        float acc[2][4];
        #pragma unroll
        for (int j = 0; j < 4; ++j) { acc[0][j] = sQW[c0 + j]; acc[1][j] = acc[0][j]; }
        #pragma unroll 8
        for (int d = 0; d < DD; d += 4) {
            const float4 k0 = *(const float4*)&sKW[r0 * 132 + d];
            const float4 k1 = *(const float4*)&sKW[(r0 + 1) * 132 + d];
            #pragma unroll
            for (int dd = 0; dd < 4; ++dd) {
                const float4 w = *(const float4*)&sWq[(d + dd) * AA + c0];
                const float ke0 = ((const float*)&k0)[dd];
                const float ke1 = ((const float*)&k1)[dd];
                acc[0][0] += ke0 * w.x; acc[0][1] += ke0 * w.y;
                acc[0][2] += ke0 * w.z; acc[0][3] += ke0 * w.w;
                acc[1][0] += ke1 * w.x; acc[1][1] += ke1 * w.y;
                acc[1][2] += ke1 * w.z; acc[1][3] += ke1 * w.w;
            }
        }
        // PReLU(a1) -> sH
        #pragma unroll
        for (int r = 0; r < 2; ++r) {
            float4 h;
            float v0 = acc[r][0]; h.x = v0 >= 0.f ? v0 : pa1 * v0;
            float v1 = acc[r][1]; h.y = v1 >= 0.f ? v1 : pa1 * v1;
            float v2 = acc[r][2]; h.z = v2 >= 0.f ? v2 : pa1 * v2;
            float v3 = acc[r][3]; h.w = v3 >= 0.f ? v3 : pa1 * v3;
            *(float4*)&sH[(r0 + r) * 68 + c0] = h;
        }
        __syncthreads();
        // W2 (64x64, row-major [a_in][a_out]) into sKW (keys tile no longer needed)
        for (int i = tid; i < (AA * AA) / 4; i += 256)
            ((float4*)sKW)[i] = ((const float4*)W2)[i];
        __syncthreads();

        // ---- GEMM2: (32 x 64) = h1(32x64) @ W2(64x64) ----
        float acc2[2][4];
        #pragma unroll
        for (int j = 0; j < 4; ++j) { acc2[0][j] = ((const float*)&bb2)[j]; acc2[1][j] = acc2[0][j]; }
        #pragma unroll 4
        for (int a = 0; a < AA; a += 4) {
            const float4 h0 = *(const float4*)&sH[r0 * 68 + a];
            const float4 h1 = *(const float4*)&sH[(r0 + 1) * 68 + a];
            #pragma unroll
            for (int dd = 0; dd < 4; ++dd) {
                const float4 w = *(const float4*)&sKW[(a + dd) * AA + c0];
                const float he0 = ((const float*)&h0)[dd];
                const float he1 = ((const float*)&h1)[dd];
                acc2[0][0] += he0 * w.x; acc2[0][1] += he0 * w.y;
                acc2[0][2] += he0 * w.z; acc2[0][3] += he0 * w.w;
                acc2[1][0] += he1 * w.x; acc2[1][1] += he1 * w.y;
                acc2[1][2] += he1 * w.z; acc2[1][3] += he1 * w.w;
            }
        }
        // PReLU(a2), layer-3 dot with W3 (b3 dropped: shift-invariant under softmax)
        #pragma unroll
        for (int r = 0; r < 2; ++r) {
            float p = 0.f;
            #pragma unroll
            for (int j = 0; j < 4; ++j) {
                float v = acc2[r][j];
                v = v >= 0.f ? v : pa2 * v;
                p += v * ((const float*)&w3v)[j];
            }
            // reduce across the 16 tc lanes (contiguous within wave)
            p += __shfl_xor(p, 1);
            p += __shfl_xor(p, 2);
            p += __shfl_xor(p, 4);
            p += __shfl_xor(p, 8);
            const int l = l0 + r0 + r;
            if (tc == 0 && l < len) sS[l] = p;
        }
    }

    __syncthreads();
    // ---- masked softmax over sS[0..199] (len==0 -> all NEG_INF -> uniform, matches ref) ----
    const int lane = tid & 63, wv = tid >> 6;
    float m = (tid < LL) ? sS[tid] : -INFINITY;
    #pragma unroll
    for (int o = 1; o < 64; o <<= 1) m = fmaxf(m, __shfl_xor(m, o));
    if (lane == 0) sRed[wv] = m;
    __syncthreads();
    const float M = fmaxf(fmaxf(sRed[0], sRed[1]), fmaxf(sRed[2], sRed[3]));
    float e = (tid < LL) ? expf(sS[tid] - M) : 0.f;
    float s = e;
    #pragma unroll
    for (int o = 1; o < 64; o <<= 1) s += __shfl_xor(s, o);
    if (lane == 0) sRed[8 + wv] = s;
    __syncthreads();
    const float S = sRed[8] + sRed[9] + sRed[10] + sRed[11];
    const float inv = 1.f / S;
    if (tid < LL) {
        const float v = e * inv;
        sS[tid] = v;
        att[(size_t)b * LL + tid] = v;
    }
    __syncthreads();

    // ---- out[b][:] = sum_l att[l] * keys[b][l][:]  (att==0 exactly for l>=len when len>0) ----
    const int Lcap = (len == 0) ? LL : len;
    float2 a3 = make_float2(0.f, 0.f);
    const float* kb = keys + (size_t)b * LL * DD + (lane << 1);
    for (int l = wv; l < Lcap; l += 4) {
        const float w = sS[l];
        const float2 kv = *(const float2*)(kb + (size_t)l * DD);
        a3.x += w * kv.x; a3.y += w * kv.y;
    }
    ((float2*)sH)[tid] = a3;
    __syncthreads();
    if (tid < 64) {
        const float2 p0 = ((float2*)sH)[tid];
        const float2 p1 = ((float2*)sH)[64 + tid];
        const float2 p2 = ((float2*)sH)[128 + tid];
        const float2 p3 = ((float2*)sH)[192 + tid];
        float2 rr;
        rr.x = p0.x + p1.x + p2.x + p3.x;
        rr.y = p0.y + p1.y + p2.y + p3.y;
        *(float2*)(out + (size_t)b * DD + (lane << 1)) = rr;
    }
}

extern "C" void kernel_launch(void* const* d_in, const int* in_sizes, int n_in,
                              void* d_out, int out_size, void* d_ws, size_t ws_size,
                              hipStream_t stream) {
    (void)in_sizes; (void)n_in; (void)d_ws; (void)ws_size; (void)out_size;
    const float* query = (const float*)d_in[0];
    const float* keys  = (const float*)d_in[1];
    const int*   klen  = (const int*)d_in[2];
    const float* W1    = (const float*)d_in[3];
    const float* b1    = (const float*)d_in[4];
    const float* a1    = (const float*)d_in[5];
    const float* W2    = (const float*)d_in[6];
    const float* b2    = (const float*)d_in[7];
    const float* a2    = (const float*)d_in[8];
    const float* W3    = (const float*)d_in[9];
    // d_in[10] = b3: provably irrelevant to both outputs (softmax shift invariance)

    float* out = (float*)d_out;                  // (B, D) fp32
    float* att = out + (size_t)NB * DD;          // (B, L) fp32

    hipLaunchKernelGGL(din_fused, dim3(NB), dim3(256), 0, stream,
                       query, keys, klen, W1, b1, a1, W2, b2, a2, W3, out, att);
}

// Round 2
// 354.325 us; speedup vs baseline: 1.3008x; 1.3008x over previous
//
#include <hip/hip_runtime.h>
#include <math.h>

typedef __attribute__((ext_vector_type(8))) _Float16 half8;
typedef __attribute__((ext_vector_type(4))) float float4_t;

#define NB 2048
#define LL 200
#define DD 128
#define AA 64
#define NEG_INF_F -4294967295.0f  // rounds to -2^32 in fp32, matches reference

#define WQ_STRIDE 136   // fp16 units: 128 + 8 pad  (byte stride 272 = 17*16, keeps b128 aligned, 2-way banks)
#define W2_STRIDE 72    // 64 + 8
#define H1_STRIDE 72    // 64 + 8

// One block per batch row. 4 waves; each wave owns independent 16-row M-tiles.
// Layer-1 fold: [q,k,q-k,q*k]@W1 = qW + k@Wq,  Wq = (W1b - W1c) + diag(q)W1d  (per-batch 128x64).
// GEMM1: keys(16x128) @ Wq -> h1 ; GEMM2: h1(16x64) @ W2 -> h2 ; layer3 dot in-register.
__global__ __launch_bounds__(256, 4)
void din_fused(const float* __restrict__ query,
               const float* __restrict__ keys,
               const int*   __restrict__ keys_length,
               const float* __restrict__ W1,
               const float* __restrict__ b1,
               const float* __restrict__ a1p,
               const float* __restrict__ W2,
               const float* __restrict__ b2,
               const float* __restrict__ a2p,
               const float* __restrict__ W3,
               float* __restrict__ out,
               float* __restrict__ att)
{
    __shared__ __align__(16) _Float16 sWqT[AA * WQ_STRIDE];     // 17408 B: Wq transposed [a][d]
    __shared__ __align__(16) _Float16 sW2T[AA * W2_STRIDE];     //  9216 B: W2 transposed [c][a]
    __shared__ __align__(16) _Float16 sH1[4 * 16 * H1_STRIDE];  //  9216 B: per-wave h1 [m][a]
    __shared__ float sQ[DD];
    __shared__ float sQW[AA];
    __shared__ float sS[224];
    __shared__ float sRed[256];

    const int tid  = threadIdx.x;
    const int b    = blockIdx.x;
    const int len  = keys_length[b];
    const float pa1 = a1p[0], pa2 = a2p[0];
    const int lane = tid & 63, wv = tid >> 6;
    const int col  = lane & 15, quad = lane >> 4;

    if (tid < DD) sQ[tid] = query[(size_t)b * DD + tid];
    for (int i = tid; i < 224; i += 256) sS[i] = NEG_INF_F;
    __syncthreads();

    // WqT[a][d] = (W1b - W1c)[d][a] + q[d]*W1d[d][a]   (W1 reads coalesced over a)
    for (int i = tid; i < DD * AA; i += 256) {
        const int d = i >> 6, a = i & 63;
        const float v = W1[(DD + d) * AA + a] - W1[(2 * DD + d) * AA + a]
                      + sQ[d] * W1[(3 * DD + d) * AA + a];
        sWqT[a * WQ_STRIDE + d] = (_Float16)v;
    }
    // W2T[c][a]
    for (int i = tid; i < AA * AA; i += 256) {
        const int a = i >> 6, c = i & 63;
        sW2T[c * W2_STRIDE + a] = (_Float16)W2[i];
    }
    // qW[a] = b1[a] + sum_d q[d]*(W1a + W1c)[d][a]  (kept fp32)
    {
        const int a = tid & 63, p = tid >> 6;
        float acc = 0.f;
        for (int d = p * 32; d < p * 32 + 32; ++d)
            acc += sQ[d] * (W1[d * AA + a] + W1[(2 * DD + d) * AA + a]);
        sRed[tid] = acc;
    }
    __syncthreads();
    if (tid < AA)
        sQW[tid] = b1[tid] + sRed[tid] + sRed[64 + tid] + sRed[128 + tid] + sRed[192 + tid];
    __syncthreads();

    // per-lane constants (constant across M-tiles)
    float qwreg[4], b2reg[4], w3reg[4];
    #pragma unroll
    for (int n = 0; n < 4; ++n) {
        qwreg[n] = sQW[n * 16 + col];
        b2reg[n] = b2[n * 16 + col];
        w3reg[n] = W3[n * 16 + col];
    }

    const int ntiles = (len + 15) >> 4;           // only score l < len; rest stays NEG_INF
    _Float16* const myH = &sH1[wv * 16 * H1_STRIDE];

    for (int t = wv; t < ntiles; t += 4) {
        const int l0 = t * 16;
        const int lrow = min(l0 + col, LL - 1);   // clamp tail rows (values masked later)
        const float* const krow = keys + ((size_t)b * LL + lrow) * DD + quad * 8;

        // ---- GEMM1: C(16x64) = keys(16x128) @ Wq(128x64), A-frags from global ----
        float4_t C[4] = {{0,0,0,0},{0,0,0,0},{0,0,0,0},{0,0,0,0}};
        #pragma unroll
        for (int ks = 0; ks < 4; ++ks) {
            const float4 a0 = *(const float4*)(krow + ks * 32);
            const float4 a1 = *(const float4*)(krow + ks * 32 + 4);
            half8 af;
            af[0] = (_Float16)a0.x; af[1] = (_Float16)a0.y;
            af[2] = (_Float16)a0.z; af[3] = (_Float16)a0.w;
            af[4] = (_Float16)a1.x; af[5] = (_Float16)a1.y;
            af[6] = (_Float16)a1.z; af[7] = (_Float16)a1.w;
            const int ko = ks * 32 + quad * 8;
            #pragma unroll
            for (int n = 0; n < 4; ++n) {
                const half8 bf = *(const half8*)&sWqT[(n * 16 + col) * WQ_STRIDE + ko];
                C[n] = __builtin_amdgcn_mfma_f32_16x16x32_f16(af, bf, C[n], 0, 0, 0);
            }
        }
        // epilogue: +qW, PReLU(a1), fp16 -> myH [m][a]
        #pragma unroll
        for (int n = 0; n < 4; ++n) {
            #pragma unroll
            for (int r = 0; r < 4; ++r) {
                float v = C[n][r] + qwreg[n];
                v = v >= 0.f ? v : pa1 * v;
                myH[(quad * 4 + r) * H1_STRIDE + n * 16 + col] = (_Float16)v;
            }
        }

        // ---- GEMM2: D(16x64) = h1(16x64) @ W2(64x64) ----
        float4_t D[4] = {{0,0,0,0},{0,0,0,0},{0,0,0,0},{0,0,0,0}};
        #pragma unroll
        for (int ks = 0; ks < 2; ++ks) {
            const int ko = ks * 32 + quad * 8;
            const half8 af = *(const half8*)&myH[col * H1_STRIDE + ko];
            #pragma unroll
            for (int n = 0; n < 4; ++n) {
                const half8 bf = *(const half8*)&sW2T[(n * 16 + col) * W2_STRIDE + ko];
                D[n] = __builtin_amdgcn_mfma_f32_16x16x32_f16(af, bf, D[n], 0, 0, 0);
            }
        }
        // layer 3: +b2, PReLU(a2), dot W3 over the 64 cols; reduce across 16 col-lanes
        float p[4] = {0.f, 0.f, 0.f, 0.f};
        #pragma unroll
        for (int n = 0; n < 4; ++n) {
            #pragma unroll
            for (int r = 0; r < 4; ++r) {
                float v = D[n][r] + b2reg[n];
                v = v >= 0.f ? v : pa2 * v;
                p[r] += v * w3reg[n];
            }
        }
        #pragma unroll
        for (int r = 0; r < 4; ++r) {
            float pv = p[r];
            pv += __shfl_xor(pv, 1);
            pv += __shfl_xor(pv, 2);
            pv += __shfl_xor(pv, 4);
            pv += __shfl_xor(pv, 8);
            const int l = l0 + quad * 4 + r;
            if (col == 0 && l < len) sS[l] = pv;   // b3 dropped: shift-invariant under softmax
        }
    }

    __syncthreads();
    // ---- masked softmax over sS[0..199] (len==0 -> all NEG_INF -> uniform, matches ref) ----
    float m = (tid < LL) ? sS[tid] : -INFINITY;
    #pragma unroll
    for (int o = 1; o < 64; o <<= 1) m = fmaxf(m, __shfl_xor(m, o));
    if (lane == 0) sRed[wv] = m;
    __syncthreads();
    const float M = fmaxf(fmaxf(sRed[0], sRed[1]), fmaxf(sRed[2], sRed[3]));
    float e = (tid < LL) ? expf(sS[tid] - M) : 0.f;
    float s = e;
    #pragma unroll
    for (int o = 1; o < 64; o <<= 1) s += __shfl_xor(s, o);
    if (lane == 0) sRed[8 + wv] = s;
    __syncthreads();
    const float S = sRed[8] + sRed[9] + sRed[10] + sRed[11];
    const float inv = 1.f / S;
    if (tid < LL) {
        const float v = e * inv;
        sS[tid] = v;
        att[(size_t)b * LL + tid] = v;
    }
    __syncthreads();

    // ---- out[b][:] = sum_l att[l] * keys[b][l][:] ----
    float2* const scratch = (float2*)sWqT;  // sWqT dead after tile loop (barrier above)
    const int Lcap = (len == 0) ? LL : len;
    float2 a3 = make_float2(0.f, 0.f);
    const float* kb = keys + (size_t)b * LL * DD + (lane << 1);
    for (int l = wv; l < Lcap; l += 4) {
        const float w = sS[l];
        const float2 kv = *(const float2*)(kb + (size_t)l * DD);
        a3.x += w * kv.x; a3.y += w * kv.y;
    }
    scratch[tid] = a3;
    __syncthreads();
    if (tid < 64) {
        const float2 p0 = scratch[tid];
        const float2 p1 = scratch[64 + tid];
        const float2 p2 = scratch[128 + tid];
        const float2 p3 = scratch[192 + tid];
        float2 rr;
        rr.x = p0.x + p1.x + p2.x + p3.x;
        rr.y = p0.y + p1.y + p2.y + p3.y;
        *(float2*)(out + (size_t)b * DD + (lane << 1)) = rr;
    }
}

extern "C" void kernel_launch(void* const* d_in, const int* in_sizes, int n_in,
                              void* d_out, int out_size, void* d_ws, size_t ws_size,
                              hipStream_t stream) {
    (void)in_sizes; (void)n_in; (void)d_ws; (void)ws_size; (void)out_size;
    const float* query = (const float*)d_in[0];
    const float* keys  = (const float*)d_in[1];
    const int*   klen  = (const int*)d_in[2];
    const float* W1    = (const float*)d_in[3];
    const float* b1    = (const float*)d_in[4];
    const float* a1    = (const float*)d_in[5];
    const float* W2    = (const float*)d_in[6];
    const float* b2    = (const float*)d_in[7];
    const float* a2    = (const float*)d_in[8];
    const float* W3    = (const float*)d_in[9];
    // d_in[10] = b3: irrelevant to both outputs (softmax shift invariance)

    float* out = (float*)d_out;                  // (B, D) fp32
    float* att = out + (size_t)NB * DD;          // (B, L) fp32

    hipLaunchKernelGGL(din_fused, dim3(NB), dim3(256), 0, stream,
                       query, keys, klen, W1, b1, a1, W2, b2, a2, W3, out, att);
}